// Round 6
// baseline (295.299 us; speedup 1.0000x reference)
//
#include <hip/hip_runtime.h>

typedef __bf16 bf16;
typedef __bf16 bf16x8 __attribute__((ext_vector_type(8)));
typedef __bf16 bf16x4 __attribute__((ext_vector_type(4)));
typedef float floatx4 __attribute__((ext_vector_type(4)));

#define MFMA_BF16(a, b, c) __builtin_amdgcn_mfma_f32_16x16x32_bf16((a), (b), (c), 0, 0, 0)

// async global->LDS, 16B per lane; LDS dest = wave-uniform base + lane*16
#define GLOAD_LDS16(gp, lp)                                      \
  __builtin_amdgcn_global_load_lds(                              \
      (const __attribute__((address_space(1))) void*)(gp),       \
      (__attribute__((address_space(3))) void*)(lp), 16, 0, 0)

// Problem constants: B=4, T=2048, C=1024, H=16, hd=64; M = B*T = 8192
#define SEQ_T 2048
#define DIM_C 1024
#define HDIM 64
#define MROWS 8192
#define N_QKV 3072

// ---------------- x fp32 -> bf16 ----------------
__global__ __launch_bounds__(256) void f32_to_bf16(
    const float* __restrict__ in, bf16* __restrict__ out) {
  const size_t i = ((size_t)blockIdx.x * 256 + threadIdx.x) * 8;
  const float4 f0 = *(const float4*)&in[i];
  const float4 f1 = *(const float4*)&in[i + 4];
  bf16x8 v;
  v[0] = (bf16)f0.x; v[1] = (bf16)f0.y; v[2] = (bf16)f0.z; v[3] = (bf16)f0.w;
  v[4] = (bf16)f1.x; v[5] = (bf16)f1.y; v[6] = (bf16)f1.z; v[7] = (bf16)f1.w;
  *(bf16x8*)&out[i] = v;
}

// ---------------- transpose fp32 -> bf16: out[N][K] = (bf16)in[K][N] ----------------
__global__ __launch_bounds__(256) void transpose_f32_bf16(
    const float* __restrict__ in, bf16* __restrict__ out, int R, int C) {
  __shared__ bf16 tile[32][33];
  const int bx = blockIdx.x * 32, by = blockIdx.y * 32;
  const int tx = threadIdx.x & 31, ty = threadIdx.x >> 5;
  for (int i = 0; i < 32; i += 8)
    tile[ty + i][tx] = (bf16)in[(size_t)(by + ty + i) * C + bx + tx];
  __syncthreads();
  for (int i = 0; i < 32; i += 8)
    out[(size_t)(bx + ty + i) * R + by + tx] = tile[tx][ty + i];
}

// ---------------- V pre-scale: V[row, h*64..] *= 2^(c2 * |K[row, h*64..]|^2) ----------------
__global__ __launch_bounds__(256) void vscale_v(bf16* __restrict__ qkv) {
  const int gtid = blockIdx.x * 256 + threadIdx.x;
  const int rh = gtid >> 3, l8 = gtid & 7;   // row-head 0..131071, lane-in-row 0..7
  const int row = rh >> 4, h = rh & 15;
  const float c2 = -0.09016844f;             // -1/16 * log2(e)
  const size_t base = (size_t)row * N_QKV + h * HDIM + l8 * 8;
  const bf16x8 kv = *(const bf16x8*)&qkv[base + 1024];
  float s = 0.f;
  for (int j = 0; j < 8; j++) { const float f = (float)kv[j]; s += f * f; }
  s += __shfl_xor(s, 1); s += __shfl_xor(s, 2); s += __shfl_xor(s, 4);
  const float vscale = exp2f(s * c2);
  bf16x8 vv = *(const bf16x8*)&qkv[base + 2048];
  for (int j = 0; j < 8; j++) vv[j] = (bf16)((float)vv[j] * vscale);
  *(bf16x8*)&qkv[base + 2048] = vv;
}

// ---------------- GEMM (m97 structure, BK=64): Cout = A @ Bt^T + bias ----------------
template <typename OT>
__global__ __launch_bounds__(256) void gemm_lds(
    const bf16* __restrict__ A,     // M x K row-major (bf16)
    const bf16* __restrict__ Bt,    // N x K row-major (bf16)
    const float* __restrict__ bias, // N (fp32)
    OT* __restrict__ Cout,          // M x N row-major
    int M, int N, int K) {
  __shared__ __align__(16) bf16 Asl[128 * 64];  // seg s: row=s>>3, phys blk=s&7
  __shared__ __align__(16) bf16 Bsl[128 * 64];  // content blk = (s&7) ^ (row&7)
  const int bm = blockIdx.y * 128, bn = blockIdx.x * 128;
  const int tid = threadIdx.x;
  const int wave = tid >> 6, lane = tid & 63;
  const int wm = (wave >> 1) * 64, wn = (wave & 1) * 64;
  const int quad = lane >> 4, l16 = lane & 15;

  const floatx4 zero = {0.f, 0.f, 0.f, 0.f};
  floatx4 acc[4][4];
  for (int i = 0; i < 4; i++)
    for (int j = 0; j < 4; j++) acc[i][j] = zero;

  // per-lane global pointers; seg s = i*256 + tid
  const bf16 *gA[4], *gB[4];
  bf16 *lA[4], *lB[4];
  for (int i = 0; i < 4; i++) {
    const int s = i * 256 + tid;
    const int row = s >> 3;
    const int c = (s & 7) ^ (row & 7);     // content block stored at phys s&7
    gA[i] = &A[(size_t)(bm + row) * K + c * 8];
    gB[i] = &Bt[(size_t)(bn + row) * K + c * 8];
    lA[i] = &Asl[(i * 256 + wave * 64) * 8];  // wave-uniform bases
    lB[i] = &Bsl[(i * 256 + wave * 64) * 8];
  }

  for (int k0 = 0; k0 < K; k0 += 64) {
    for (int i = 0; i < 4; i++) GLOAD_LDS16(gA[i] + k0, lA[i]);
    for (int i = 0; i < 4; i++) GLOAD_LDS16(gB[i] + k0, lB[i]);
    __syncthreads();
    for (int kk = 0; kk < 2; kk++) {
      bf16x8 af[4], bfr[4];
      for (int it = 0; it < 4; it++) {
        const int row = wm + it * 16 + l16;
        const int phys = (kk * 4 + quad) ^ (row & 7);
        af[it] = *(const bf16x8*)&Asl[row * 64 + phys * 8];
      }
      for (int jt = 0; jt < 4; jt++) {
        const int row = wn + jt * 16 + l16;
        const int phys = (kk * 4 + quad) ^ (row & 7);
        bfr[jt] = *(const bf16x8*)&Bsl[row * 64 + phys * 8];
      }
      for (int it = 0; it < 4; it++)
        for (int jt = 0; jt < 4; jt++)
          acc[it][jt] = MFMA_BF16(af[it], bfr[jt], acc[it][jt]);
    }
    __syncthreads();
  }
  // C/D layout: row = quad*4+reg, col = l16
  for (int jt = 0; jt < 4; jt++) {
    const int col = bn + wn + jt * 16 + l16;
    const float bv = bias[col];
    for (int it = 0; it < 4; it++)
      for (int r = 0; r < 4; r++) {
        const int row = bm + wm + it * 16 + quad * 4 + r;
        Cout[(size_t)row * N + col] = (OT)(acc[it][jt][r] + bv);
      }
  }
}

// ---------------- attention (swapped QK^T -> b64 Ps writes) ----------------
// DS-pipe is the measured bottleneck (~542 cyc/wave-iter of LDS instruction
// cost x 16 waves/CU matches the wall). Biggest narrow-op block was the Ps
// scatter: 32 ds_write_b16/thread-iter. Fix: compute QK^T SWAPPED
// (mfma(K,Q) -> accs[T][jt][r] = S[q=wave*16+l16][k=jt*16+quad*4+r]; layout
// hardware-verified in R2) so each thread holds 4 CONSECUTIVE k per (T,jt)
// for one q-row -> Ps store becomes 8 ds_write_b64 (bf16x4) into the SAME
// logical Ps[q][k]. PV read side unchanged from proven R4 code (b128 reads,
// no swizzle). Bank check: b64 writes pair only (l16,l16+8) -> 2-way = free.
// Grid stays XCD-affine (bh fastest): FETCH 53 MB. T14 prefetch kept.
// LDS 37.5 KB -> 4 blocks/CU.
__global__ __launch_bounds__(256, 4) void attn_kernel(
    const bf16* __restrict__ qkv,  // 8192 x 3072 : [q | k | v-prescaled]
    bf16* __restrict__ y) {        // 8192 x 1024
  const int p = blockIdx.y;            // 0..15  (paired-triangle pair index)
  const int bh = blockIdx.x;           // 0..63  (XCD-affine: bh%8 pins XCD)
  const int bb = bh >> 4, h = bh & 15;
  const int qtA = p, qtB = 31 - p;
  const int tid = threadIdx.x;
  const int wave = tid >> 6, lane = tid & 63;
  const int quad = lane >> 4, l16 = lane & 15;

  __shared__ __align__(16) bf16 Ps[128][72];   // [q-local (A:0..63,B:64..127)][k]
  __shared__ __align__(16) bf16 Ks[64][72];
  __shared__ __align__(16) bf16 Vt[64][72];    // [d][key ^ (d & 0x38)], pre-scaled
  __shared__ float q2c[128];                   // c2 * |q|^2 per q-row (wave-private)

  const size_t rowbase = (size_t)bb * SEQ_T;
  const float c2 = -0.09016844f;    // -1/16 * log2(e)
  const float m2c2 = 0.18033688f;   // -2*c2

  // ---- Q fragments in registers + q2c (shfl across quads) ----
  bf16x8 aq[2][2];
  for (int T = 0; T < 2; T++) {
    const int qt = T ? qtB : qtA;
    const size_t grow = rowbase + qt * 64 + wave * 16 + l16;
    float s = 0.f;
    for (int ks = 0; ks < 2; ks++) {
      aq[T][ks] = *(const bf16x8*)&qkv[grow * N_QKV + h * HDIM + ks * 32 + quad * 8];
      for (int j = 0; j < 8; j++) { const float f = (float)aq[T][ks][j]; s += f * f; }
    }
    s += __shfl_xor(s, 16); s += __shfl_xor(s, 32);
    if (quad == 0) q2c[T * 64 + wave * 16 + l16] = s * c2;
  }

  const floatx4 zero = {0.f, 0.f, 0.f, 0.f};
  floatx4 accy[2][4];
  for (int T = 0; T < 2; T++)
    for (int jt = 0; jt < 4; jt++) accy[T][jt] = zero;

  // ---- staging addresses + preload of tile kt=0 into registers (T14) ----
  const int r0 = tid >> 3, c8 = (tid & 7) << 3;
  const bf16* kgp = &qkv[(rowbase + r0) * N_QKV + 1024 + h * HDIM + c8];
  const size_t istep = (size_t)32 * N_QKV;     // i: +32 rows
  const size_t kstep = (size_t)64 * N_QKV;     // kt: +64 rows
  bf16x8 kreg[2], vreg[2];
  for (int i = 0; i < 2; i++) {
    kreg[i] = *(const bf16x8*)&kgp[i * istep];
    vreg[i] = *(const bf16x8*)&kgp[i * istep + 1024];
  }

  const int qrow = wave * 16 + l16;   // this lane's local q-row (both tiles)

  for (int kt = 0; kt <= qtB; kt++) {
    const bool actA = (kt <= qtA);
    if (kt) __syncthreads();   // previous iter's Ks/Vt reads done
    // ---- write staged regs to LDS: K row-major; V transposed+swizzled ----
    for (int i = 0; i < 2; i++) {
      const int r = r0 + i * 32;
      *(bf16x8*)&Ks[r][c8] = kreg[i];
      for (int j = 0; j < 8; j++)
        Vt[c8 + j][r ^ c8] = vreg[i][j];
    }
    __syncthreads();  // staging visible

    // ---- issue loads for kt+1; latency hides under the compute below ----
    if (kt < qtB) {
      const bf16* kp = kgp + (size_t)(kt + 1) * kstep;
      for (int i = 0; i < 2; i++) {
        kreg[i] = *(const bf16x8*)&kp[i * istep];
        vreg[i] = *(const bf16x8*)&kp[i * istep + 1024];
      }
    }

    // ---- S^T = K.Q^T (swapped; R2-verified):
    //      accs[T][jt][r] = S[q=wave*16+l16][k=jt*16+quad*4+r] ----
    bf16x8 bk[4][2];
    for (int jt = 0; jt < 4; jt++)
      for (int ks = 0; ks < 2; ks++)
        bk[jt][ks] = *(const bf16x8*)&Ks[jt * 16 + l16][ks * 32 + quad * 8];
    floatx4 accs[2][4];
    for (int T = 0; T < 2; T++)
      for (int jt = 0; jt < 4; jt++) accs[T][jt] = zero;
    for (int T = 0; T < 2; T++) {
      if (T == 0 && !actA) continue;
      for (int ks = 0; ks < 2; ks++)
        for (int jt = 0; jt < 4; jt++)
          accs[T][jt] = MFMA_BF16(bk[jt][ks], aq[T][ks], accs[T][jt]);
    }

    // ---- P̂ = 2^(m2c2*qk), mask on diagonal tile; b64 writes (4 consec k) ----
    for (int T = 0; T < 2; T++) {
      if (T == 0 && !actA) continue;
      const bool diag = (kt == (T == 0 ? qtA : qtB));
      for (int jt = 0; jt < 4; jt++) {
        const int kb = jt * 16 + quad * 4;
        bf16x4 pw;
        for (int r = 0; r < 4; r++) {
          float pe = exp2f(m2c2 * accs[T][jt][r]);
          if (diag && kb + r > qrow) pe = 0.f;
          pw[r] = (bf16)pe;
        }
        *(bf16x4*)&Ps[T * 64 + qrow][kb] = pw;
      }
    }

    // ---- y += P̂ . Ṽ (bv loaded once, used by both tiles) ----
    bf16x8 bv[4][2];
    for (int jt = 0; jt < 4; jt++)
      for (int ks = 0; ks < 2; ks++) {
        const int d = jt * 16 + l16;
        bv[jt][ks] = *(const bf16x8*)&Vt[d][(ks * 32 + quad * 8) ^ (d & 0x38)];
      }
    for (int T = 0; T < 2; T++) {
      if (T == 0 && !actA) continue;
      for (int ks = 0; ks < 2; ks++) {
        const bf16x8 ap =
            *(const bf16x8*)&Ps[T * 64 + qrow][ks * 32 + quad * 8];
        for (int jt = 0; jt < 4; jt++)
          accy[T][jt] = MFMA_BF16(ap, bv[jt][ks], accy[T][jt]);
      }
    }
  }

  // ---- epilogue: scale by 2^(c2*q2), store ----
  for (int T = 0; T < 2; T++) {
    const int qt = (T == 0) ? qtA : qtB;
    float ysc[4];
    for (int r = 0; r < 4; r++)
      ysc[r] = exp2f(q2c[T * 64 + wave * 16 + quad * 4 + r]);
    for (int jt = 0; jt < 4; jt++) {
      const int col = h * HDIM + jt * 16 + l16;
      for (int r = 0; r < 4; r++) {
        const int ml = wave * 16 + quad * 4 + r;
        y[(rowbase + qt * 64 + ml) * DIM_C + col] = (bf16)(accy[T][jt][r] * ysc[r]);
      }
    }
  }
}

extern "C" void kernel_launch(void* const* d_in, const int* in_sizes, int n_in,
                              void* d_out, int out_size, void* d_ws, size_t ws_size,
                              hipStream_t stream) {
  const float* x      = (const float*)d_in[0];  // 8192 x 1024 fp32
  const float* W_attn = (const float*)d_in[1];  // 1024 x 3072 fp32
  const float* b_attn = (const float*)d_in[2];  // 3072 fp32
  const float* W_proj = (const float*)d_in[3];  // 1024 x 1024 fp32
  const float* b_proj = (const float*)d_in[4];  // 1024 fp32
  float* out = (float*)d_out;                   // 8192 x 1024 fp32

  char* ws = (char*)d_ws;
  bf16* qkv = (bf16*)(ws);             // 50,331,648 B
  bf16* yb  = (bf16*)(ws + 50331648);  // 16,777,216 B — also holds xb before attn
  bf16* WaT = (bf16*)(ws + 67108864);  //  6,291,456 B
  bf16* WpT = (bf16*)(ws + 73400320);  //  2,097,152 B  (total 75,497,472)
  bf16* xb  = yb;                      // x-bf16 is dead before attn writes yb

  f32_to_bf16<<<dim3(4096), 256, 0, stream>>>(x, xb);
  transpose_f32_bf16<<<dim3(96, 32), 256, 0, stream>>>(W_attn, WaT, 1024, 3072);
  transpose_f32_bf16<<<dim3(32, 32), 256, 0, stream>>>(W_proj, WpT, 1024, 1024);
  gemm_lds<bf16><<<dim3(24, 64), 256, 0, stream>>>(
      xb, WaT, b_attn, qkv, MROWS, N_QKV, DIM_C);
  vscale_v<<<dim3(4096), 256, 0, stream>>>(qkv);
  attn_kernel<<<dim3(64, 16), 256, 0, stream>>>(qkv, yb);
  gemm_lds<float><<<dim3(8, 64), 256, 0, stream>>>(
      yb, WpT, b_proj, out, MROWS, DIM_C, DIM_C);
}

// Round 8
// 289.534 us; speedup vs baseline: 1.0199x; 1.0199x over previous
//
#include <hip/hip_runtime.h>

typedef __bf16 bf16;
typedef __bf16 bf16x8 __attribute__((ext_vector_type(8)));
typedef __bf16 bf16x4 __attribute__((ext_vector_type(4)));
typedef float floatx4 __attribute__((ext_vector_type(4)));

#define MFMA_BF16(a, b, c) __builtin_amdgcn_mfma_f32_16x16x32_bf16((a), (b), (c), 0, 0, 0)

// async global->LDS, 16B per lane; LDS dest = wave-uniform base + lane*16
#define GLOAD_LDS16(gp, lp)                                      \
  __builtin_amdgcn_global_load_lds(                              \
      (const __attribute__((address_space(1))) void*)(gp),       \
      (__attribute__((address_space(3))) void*)(lp), 16, 0, 0)

// Problem constants: B=4, T=2048, C=1024, H=16, hd=64; M = B*T = 8192
#define SEQ_T 2048
#define DIM_C 1024
#define HDIM 64
#define MROWS 8192
#define N_QKV 3072

// ---------------- x fp32 -> bf16 ----------------
__global__ __launch_bounds__(256) void f32_to_bf16(
    const float* __restrict__ in, bf16* __restrict__ out) {
  const size_t i = ((size_t)blockIdx.x * 256 + threadIdx.x) * 8;
  const float4 f0 = *(const float4*)&in[i];
  const float4 f1 = *(const float4*)&in[i + 4];
  bf16x8 v;
  v[0] = (bf16)f0.x; v[1] = (bf16)f0.y; v[2] = (bf16)f0.z; v[3] = (bf16)f0.w;
  v[4] = (bf16)f1.x; v[5] = (bf16)f1.y; v[6] = (bf16)f1.z; v[7] = (bf16)f1.w;
  *(bf16x8*)&out[i] = v;
}

// ---------------- transpose fp32 -> bf16: out[N][K] = (bf16)in[K][N] ----------------
__global__ __launch_bounds__(256) void transpose_f32_bf16(
    const float* __restrict__ in, bf16* __restrict__ out, int R, int C) {
  __shared__ bf16 tile[32][33];
  const int bx = blockIdx.x * 32, by = blockIdx.y * 32;
  const int tx = threadIdx.x & 31, ty = threadIdx.x >> 5;
  for (int i = 0; i < 32; i += 8)
    tile[ty + i][tx] = (bf16)in[(size_t)(by + ty + i) * C + bx + tx];
  __syncthreads();
  for (int i = 0; i < 32; i += 8)
    out[(size_t)(bx + ty + i) * R + by + tx] = tile[tx][ty + i];
}

// ---------------- V scale+transpose pre-pass ----------------
// Replaces vscale_v: reads K,V (interleaved qkv), writes VT[bh][d=64][key=2048]
// with V^T rows scaled by 2^(c2*|K-row|^2). Scale math bitwise-identical to the
// old vscale_v (8-elem partials + shfl_xor 1/2/4). One 64key x 64d tile/block.
__global__ __launch_bounds__(256) void scale_transpose_v(
    const bf16* __restrict__ qkv, bf16* __restrict__ VT) {
  const int bh = blockIdx.x;       // 0..63
  const int kt = blockIdx.y;       // 0..31
  const int bb = bh >> 4, h = bh & 15;
  const int tid = threadIdx.x;
  __shared__ bf16 tile[64][72];    // [d][key ^ (d & 0x38)]
  const int r0 = tid >> 3, c8 = (tid & 7) << 3;
  const float c2 = -0.09016844f;   // -1/16 * log2(e)
  for (int i = 0; i < 2; i++) {
    const int r = r0 + i * 32;
    const size_t gr = (size_t)bb * SEQ_T + kt * 64 + r;
    const bf16x8 kv = *(const bf16x8*)&qkv[gr * N_QKV + 1024 + h * HDIM + c8];
    float s = 0.f;
    for (int j = 0; j < 8; j++) { const float f = (float)kv[j]; s += f * f; }
    s += __shfl_xor(s, 1); s += __shfl_xor(s, 2); s += __shfl_xor(s, 4);
    const float vscale = exp2f(s * c2);
    const bf16x8 vv = *(const bf16x8*)&qkv[gr * N_QKV + 2048 + h * HDIM + c8];
    for (int j = 0; j < 8; j++)
      tile[c8 + j][r ^ c8] = (bf16)((float)vv[j] * vscale);
  }
  __syncthreads();
  for (int i = 0; i < 2; i++) {
    const int u = i * 256 + tid;
    const int d = u >> 3, kc = (u & 7) << 3;
    const bf16x8 ov = *(const bf16x8*)&tile[d][kc ^ (d & 0x38)];
    *(bf16x8*)&VT[(size_t)bh * 131072 + (size_t)d * 2048 + kt * 64 + kc] = ov;
  }
}

// ---------------- GEMM (m97 structure, BK=64): Cout = A @ Bt^T + bias ----------------
// lda added so gemm2 can read attn output in-place from qkv's V-third (lda=3072).
template <typename OT>
__global__ __launch_bounds__(256) void gemm_lds(
    const bf16* __restrict__ A,     // M x K row-major (bf16), row stride lda
    const bf16* __restrict__ Bt,    // N x K row-major (bf16)
    const float* __restrict__ bias, // N (fp32)
    OT* __restrict__ Cout,          // M x N row-major
    int M, int N, int K, int lda) {
  __shared__ __align__(16) bf16 Asl[128 * 64];  // seg s: row=s>>3, phys blk=s&7
  __shared__ __align__(16) bf16 Bsl[128 * 64];  // content blk = (s&7) ^ (row&7)
  const int bm = blockIdx.y * 128, bn = blockIdx.x * 128;
  const int tid = threadIdx.x;
  const int wave = tid >> 6, lane = tid & 63;
  const int wm = (wave >> 1) * 64, wn = (wave & 1) * 64;
  const int quad = lane >> 4, l16 = lane & 15;

  const floatx4 zero = {0.f, 0.f, 0.f, 0.f};
  floatx4 acc[4][4];
  for (int i = 0; i < 4; i++)
    for (int j = 0; j < 4; j++) acc[i][j] = zero;

  // per-lane global pointers; seg s = i*256 + tid
  const bf16 *gA[4], *gB[4];
  bf16 *lA[4], *lB[4];
  for (int i = 0; i < 4; i++) {
    const int s = i * 256 + tid;
    const int row = s >> 3;
    const int c = (s & 7) ^ (row & 7);     // content block stored at phys s&7
    gA[i] = &A[(size_t)(bm + row) * lda + c * 8];
    gB[i] = &Bt[(size_t)(bn + row) * K + c * 8];
    lA[i] = &Asl[(i * 256 + wave * 64) * 8];  // wave-uniform bases
    lB[i] = &Bsl[(i * 256 + wave * 64) * 8];
  }

  for (int k0 = 0; k0 < K; k0 += 64) {
    for (int i = 0; i < 4; i++) GLOAD_LDS16(gA[i] + k0, lA[i]);
    for (int i = 0; i < 4; i++) GLOAD_LDS16(gB[i] + k0, lB[i]);
    __syncthreads();
    for (int kk = 0; kk < 2; kk++) {
      bf16x8 af[4], bfr[4];
      for (int it = 0; it < 4; it++) {
        const int row = wm + it * 16 + l16;
        const int phys = (kk * 4 + quad) ^ (row & 7);
        af[it] = *(const bf16x8*)&Asl[row * 64 + phys * 8];
      }
      for (int jt = 0; jt < 4; jt++) {
        const int row = wn + jt * 16 + l16;
        const int phys = (kk * 4 + quad) ^ (row & 7);
        bfr[jt] = *(const bf16x8*)&Bsl[row * 64 + phys * 8];
      }
      for (int it = 0; it < 4; it++)
        for (int jt = 0; jt < 4; jt++)
          acc[it][jt] = MFMA_BF16(af[it], bfr[jt], acc[it][jt]);
    }
    __syncthreads();
  }
  // C/D layout: row = quad*4+reg, col = l16
  for (int jt = 0; jt < 4; jt++) {
    const int col = bn + wn + jt * 16 + l16;
    const float bv = bias[col];
    for (int it = 0; it < 4; it++)
      for (int r = 0; r < 4; r++) {
        const int row = bm + wm + it * 16 + quad * 4 + r;
        Cout[(size_t)row * N + col] = (OT)(acc[it][jt][r] + bv);
      }
  }
}

// ---------------- attention (R6 math + gload_lds dbuf staging) ----------------
// Compute path (QK^T swapped, b64 Ps writes, b128 PV reads, epilogue scale) is
// byte-identical to R6 (passing, absmax 0.03125). Staging rewritten:
//  - K and pre-transposed V (VT) staged via 4 global_load_lds/thread/tile into
//    double-buffered Ksl/Vsl[2][64*64] with the gemm-proven XOR-8 swizzled
//    SOURCE (content blk c = (tid&7) ^ (r0&7)); fragment reads use
//    phys = (ks*4+quad) ^ (l16&7)  -> 2-way banks (free).
//  - ONE barrier/iter: __syncthreads' implicit vmcnt(0) drains the PREVIOUS
//    iter's prefetch (a full compute phase of latency hiding); next tile is
//    issued right after the barrier into the other buffer (its readers all
//    finished before the barrier by program order -> no race).
// Output y goes into qkv's V-third (dead after the VT pre-pass); gemm2 reads
// it with lda=3072. LDS: Ps 18.4K + 2x8K K + 2x8K V + q2c = 51.7 KB -> 3 blk/CU.
__global__ __launch_bounds__(256, 4) void attn_kernel(
    bf16* __restrict__ qkv,        // 8192 x 3072 : [q | k | y-out]
    const bf16* __restrict__ VT) { // [bh][64 d][2048 key], k2-scaled
  const int p = blockIdx.y;            // 0..15  (paired-triangle pair index)
  const int bh = blockIdx.x;           // 0..63  (XCD-affine: bh%8 pins XCD)
  const int bb = bh >> 4, h = bh & 15;
  const int qtA = p, qtB = 31 - p;
  const int tid = threadIdx.x;
  const int wave = tid >> 6, lane = tid & 63;
  const int quad = lane >> 4, l16 = lane & 15;

  __shared__ __align__(16) bf16 Ps[128][72];     // [q-local (A:0..63,B:64..127)][k]
  __shared__ __align__(16) bf16 Ksl[2][64 * 64]; // [row][phys blk], c = phys ^ (row&7)
  __shared__ __align__(16) bf16 Vsl[2][64 * 64]; // [d][phys blk],   c = phys ^ (d&7)
  __shared__ float q2c[128];                     // c2 * |q|^2 per q-row

  const size_t rowbase = (size_t)bb * SEQ_T;
  const float c2 = -0.09016844f;    // -1/16 * log2(e)
  const float m2c2 = 0.18033688f;   // -2*c2

  // ---- Q fragments in registers + q2c (shfl across quads) ----
  bf16x8 aq[2][2];
  for (int T = 0; T < 2; T++) {
    const int qt = T ? qtB : qtA;
    const size_t grow = rowbase + qt * 64 + wave * 16 + l16;
    float s = 0.f;
    for (int ks = 0; ks < 2; ks++) {
      aq[T][ks] = *(const bf16x8*)&qkv[grow * N_QKV + h * HDIM + ks * 32 + quad * 8];
      for (int j = 0; j < 8; j++) { const float f = (float)aq[T][ks][j]; s += f * f; }
    }
    s += __shfl_xor(s, 16); s += __shfl_xor(s, 32);
    if (quad == 0) q2c[T * 64 + wave * 16 + l16] = s * c2;
  }

  const floatx4 zero = {0.f, 0.f, 0.f, 0.f};
  floatx4 accy[2][4];
  for (int T = 0; T < 2; T++)
    for (int jt = 0; jt < 4; jt++) accy[T][jt] = zero;

  // ---- staging source addresses (XOR-8 swizzled content block) ----
  const int r0 = tid >> 3;                       // row / d (both i share &7)
  const int cb = (tid & 7) ^ (r0 & 7);           // content block
  const bf16* gK = &qkv[(rowbase + r0) * N_QKV + 1024 + h * HDIM + cb * 8];
  const bf16* gV = &VT[(size_t)bh * 131072 + (size_t)r0 * 2048 + cb * 8];

#define STAGE(kt_, nb_) do {                                            \
    const size_t ko = (size_t)(kt_) * 64 * N_QKV;                       \
    const int vo = (kt_) * 64;                                          \
    GLOAD_LDS16(gK + ko,                    &Ksl[nb_][(wave * 64) * 8]);\
    GLOAD_LDS16(gK + ko + (size_t)32 * N_QKV,                           \
                &Ksl[nb_][(256 + wave * 64) * 8]);                      \
    GLOAD_LDS16(gV + vo,                    &Vsl[nb_][(wave * 64) * 8]);\
    GLOAD_LDS16(gV + vo + 32 * 2048,        &Vsl[nb_][(256 + wave * 64) * 8]);\
  } while (0)

  STAGE(0, 0);
  int cur = 0;
  const int qrow = wave * 16 + l16;   // this lane's local q-row (both tiles)

  for (int kt = 0; kt <= qtB; kt++) {
    const bool actA = (kt <= qtA);
    __syncthreads();   // implicit vmcnt(0): tile kt landed; prev-buf reads done
    if (kt < qtB) STAGE(kt + 1, cur ^ 1);
    const bf16* Kb = Ksl[cur];
    const bf16* Vb = Vsl[cur];

    // ---- S^T = K.Q^T (swapped; R6-verified):
    //      accs[T][jt][r] = S[q=wave*16+l16][k=jt*16+quad*4+r] ----
    bf16x8 bk[4][2];
    for (int jt = 0; jt < 4; jt++)
      for (int ks = 0; ks < 2; ks++) {
        const int phys = (ks * 4 + quad) ^ (l16 & 7);
        bk[jt][ks] = *(const bf16x8*)&Kb[(jt * 16 + l16) * 64 + phys * 8];
      }
    floatx4 accs[2][4];
    for (int T = 0; T < 2; T++)
      for (int jt = 0; jt < 4; jt++) accs[T][jt] = zero;
    for (int T = 0; T < 2; T++) {
      if (T == 0 && !actA) continue;
      for (int ks = 0; ks < 2; ks++)
        for (int jt = 0; jt < 4; jt++)
          accs[T][jt] = MFMA_BF16(bk[jt][ks], aq[T][ks], accs[T][jt]);
    }

    // ---- P̂ = 2^(m2c2*qk), mask on diagonal tile; b64 writes (4 consec k) ----
    for (int T = 0; T < 2; T++) {
      if (T == 0 && !actA) continue;
      const bool diag = (kt == (T == 0 ? qtA : qtB));
      for (int jt = 0; jt < 4; jt++) {
        const int kb = jt * 16 + quad * 4;
        bf16x4 pw;
        for (int r = 0; r < 4; r++) {
          float pe = exp2f(m2c2 * accs[T][jt][r]);
          if (diag && kb + r > qrow) pe = 0.f;
          pw[r] = (bf16)pe;
        }
        *(bf16x4*)&Ps[T * 64 + qrow][kb] = pw;
      }
    }

    // ---- y += P̂ . Ṽ (bv loaded once, used by both tiles) ----
    bf16x8 bv[4][2];
    for (int dt = 0; dt < 4; dt++)
      for (int ks = 0; ks < 2; ks++) {
        const int phys = (ks * 4 + quad) ^ (l16 & 7);
        bv[dt][ks] = *(const bf16x8*)&Vb[(dt * 16 + l16) * 64 + phys * 8];
      }
    for (int T = 0; T < 2; T++) {
      if (T == 0 && !actA) continue;
      for (int ks = 0; ks < 2; ks++) {
        const bf16x8 ap =
            *(const bf16x8*)&Ps[T * 64 + qrow][ks * 32 + quad * 8];
        for (int jt = 0; jt < 4; jt++)
          accy[T][jt] = MFMA_BF16(ap, bv[jt][ks], accy[T][jt]);
      }
    }
    cur ^= 1;
  }
#undef STAGE

  // ---- epilogue: scale by 2^(c2*q2), store into qkv V-third (stride 3072) ----
  for (int T = 0; T < 2; T++) {
    const int qt = (T == 0) ? qtA : qtB;
    float ysc[4];
    for (int r = 0; r < 4; r++)
      ysc[r] = exp2f(q2c[T * 64 + wave * 16 + quad * 4 + r]);
    for (int jt = 0; jt < 4; jt++) {
      const int col = h * HDIM + jt * 16 + l16;
      for (int r = 0; r < 4; r++) {
        const int ml = wave * 16 + quad * 4 + r;
        qkv[(rowbase + qt * 64 + ml) * N_QKV + 2048 + col] =
            (bf16)(accy[T][jt][r] * ysc[r]);
      }
    }
  }
}

extern "C" void kernel_launch(void* const* d_in, const int* in_sizes, int n_in,
                              void* d_out, int out_size, void* d_ws, size_t ws_size,
                              hipStream_t stream) {
  const float* x      = (const float*)d_in[0];  // 8192 x 1024 fp32
  const float* W_attn = (const float*)d_in[1];  // 1024 x 3072 fp32
  const float* b_attn = (const float*)d_in[2];  // 3072 fp32
  const float* W_proj = (const float*)d_in[3];  // 1024 x 1024 fp32
  const float* b_proj = (const float*)d_in[4];  // 1024 fp32
  float* out = (float*)d_out;                   // 8192 x 1024 fp32

  char* ws = (char*)d_ws;
  bf16* qkv = (bf16*)(ws);             // 50,331,648 B  [q|k|v -> q|k|y]
  bf16* VTb = (bf16*)(ws + 50331648);  // 16,777,216 B — holds xb before pre-pass
  bf16* WaT = (bf16*)(ws + 67108864);  //  6,291,456 B
  bf16* WpT = (bf16*)(ws + 73400320);  //  2,097,152 B  (total 75,497,472)
  bf16* xb  = VTb;                     // x-bf16 dead before scale_transpose_v

  f32_to_bf16<<<dim3(4096), 256, 0, stream>>>(x, xb);
  transpose_f32_bf16<<<dim3(96, 32), 256, 0, stream>>>(W_attn, WaT, 1024, 3072);
  transpose_f32_bf16<<<dim3(32, 32), 256, 0, stream>>>(W_proj, WpT, 1024, 1024);
  gemm_lds<bf16><<<dim3(24, 64), 256, 0, stream>>>(
      xb, WaT, b_attn, qkv, MROWS, N_QKV, DIM_C, DIM_C);
  scale_transpose_v<<<dim3(64, 32), 256, 0, stream>>>(qkv, VTb);
  attn_kernel<<<dim3(64, 16), 256, 0, stream>>>(qkv, VTb);
  gemm_lds<float><<<dim3(8, 64), 256, 0, stream>>>(
      qkv + 2048, WpT, b_proj, out, MROWS, DIM_C, DIM_C, N_QKV);
}